// Round 1
// baseline (472.127 us; speedup 1.0000x reference)
//
#include <hip/hip_runtime.h>

// ---------------------------------------------------------------------------
// MHABlock: Q/K/V proj (bf16 MFMA) -> flash attention (no-max online softmax,
// legal since logits ~N(0,0.125^2)) -> residual + LayerNorm.
// Raw-reshape quirks handled by flat-index permutations:
//   Qh[h][n][k] = Qflat[h*262144 + n*64 + k]        (natural)
//   Kh[h][k][m] = Kflat[h*262144 + k*4096 + m]  -> stored K'[h][m][k]
//   Vh[h][m][k] = Vflat[h*262144 + m*64 + k]    -> stored V'[h][k][m]
// so all MFMA fragments are 16B-contiguous loads.
// ---------------------------------------------------------------------------

typedef __bf16 bf16x8 __attribute__((ext_vector_type(8)));
typedef float  f32x4  __attribute__((ext_vector_type(4)));

#define N_TOK   4096
#define D_MODEL 640
#define DK      64
#define HSLAB   (N_TOK * DK)   // 262144 elements per head slab

__device__ __forceinline__ unsigned short f2bf(float f) {
    unsigned int u = __builtin_bit_cast(unsigned int, f);
    u += 0x7fffu + ((u >> 16) & 1u);          // round-to-nearest-even
    return (unsigned short)(u >> 16);
}

// -------------------------------- fp32 -> bf16 -----------------------------
__global__ __launch_bounds__(256) void cvt_bf16(const float* __restrict__ src,
                                                unsigned short* __restrict__ dst,
                                                int n4) {
    int i = blockIdx.x * 256 + threadIdx.x;
    if (i < n4) {
        float4 v = ((const float4*)src)[i];
        ushort4 o;
        o.x = f2bf(v.x); o.y = f2bf(v.y); o.z = f2bf(v.z); o.w = f2bf(v.w);
        ((ushort4*)dst)[i] = o;
    }
}

// ------------------------ QKV NT-GEMM: C = x @ W^T -------------------------
// M=4096, N=640, K=640. 128x128 tile, BK=32, 4 waves each 64x64.
// mode 0: Q identity store; mode 1: K' permute; mode 2: V' permute.
#define BM  128
#define BN  128
#define BKK 32
#define LDT 40   // padded LDS stride (elements); 80B rows -> conflict-friendly

__global__ __launch_bounds__(256, 2) void gemm_qkv(
    const unsigned short* __restrict__ xb,
    const unsigned short* __restrict__ wq,
    const unsigned short* __restrict__ wk,
    const unsigned short* __restrict__ wv,
    unsigned short* __restrict__ Qo,
    unsigned short* __restrict__ Ko,
    unsigned short* __restrict__ Vo) {
    const int mode = blockIdx.z;
    const unsigned short* W = (mode == 0) ? wq : (mode == 1) ? wk : wv;
    unsigned short*       C = (mode == 0) ? Qo : (mode == 1) ? Ko : Vo;
    const int m0 = blockIdx.y * BM;
    const int n0 = blockIdx.x * BN;

    __shared__ unsigned short As[BM * LDT];
    __shared__ unsigned short Bs[BN * LDT];

    const int tid  = threadIdx.x;
    const int lane = tid & 63;
    const int wave = tid >> 6;
    const int quad = lane >> 4, l16 = lane & 15;
    const int wm = (wave >> 1) * 64, wn = (wave & 1) * 64;

    f32x4 acc[4][4] = {};

    // staging: 512 16B chunks per tile, 2 per thread
    const int c0 = tid, c1 = tid + 256;
    const int r0 = c0 >> 2, k0o = (c0 & 3) << 3;
    const int r1 = c1 >> 2, k1o = (c1 & 3) << 3;

    for (int kt = 0; kt < D_MODEL; kt += BKK) {
        __syncthreads();
        *(bf16x8*)&As[r0 * LDT + k0o] = *(const bf16x8*)&xb[(size_t)(m0 + r0) * D_MODEL + kt + k0o];
        *(bf16x8*)&As[r1 * LDT + k1o] = *(const bf16x8*)&xb[(size_t)(m0 + r1) * D_MODEL + kt + k1o];
        *(bf16x8*)&Bs[r0 * LDT + k0o] = *(const bf16x8*)&W [(size_t)(n0 + r0) * D_MODEL + kt + k0o];
        *(bf16x8*)&Bs[r1 * LDT + k1o] = *(const bf16x8*)&W [(size_t)(n0 + r1) * D_MODEL + kt + k1o];
        __syncthreads();

        bf16x8 af[4], bfr[4];
        for (int mi = 0; mi < 4; mi++)
            af[mi] = *(const bf16x8*)&As[(wm + mi * 16 + l16) * LDT + quad * 8];
        for (int ni = 0; ni < 4; ni++)
            bfr[ni] = *(const bf16x8*)&Bs[(wn + ni * 16 + l16) * LDT + quad * 8];
        for (int mi = 0; mi < 4; mi++)
            for (int ni = 0; ni < 4; ni++)
                acc[mi][ni] = __builtin_amdgcn_mfma_f32_16x16x32_bf16(af[mi], bfr[ni], acc[mi][ni], 0, 0, 0);
    }

    // epilogue: C/D layout row = quad*4+r, col = l16
    for (int mi = 0; mi < 4; mi++)
        for (int ni = 0; ni < 4; ni++)
            for (int r = 0; r < 4; r++) {
                int row = m0 + wm + mi * 16 + quad * 4 + r;
                int col = n0 + wn + ni * 16 + l16;
                unsigned idx = (unsigned)row * D_MODEL + col;
                unsigned dst;
                if (mode == 0) {
                    dst = idx;
                } else {
                    unsigned h = idx / HSLAB, rr = idx % HSLAB;
                    if (mode == 1) { unsigned k = rr / N_TOK, m = rr % N_TOK; dst = h * HSLAB + m * DK + k; }
                    else           { unsigned m = rr / DK,   k = rr % DK;    dst = h * HSLAB + k * N_TOK + m; }
                }
                C[dst] = f2bf(acc[mi][ni][r]);
            }
}

// ------------------------------- attention ---------------------------------
// One block = (head, 64-row Q tile). 4 waves, each owns 16 Q rows.
// Per iteration (Bk=64 key columns): S = Q*K'^T (8 MFMA), exp, P->LDS,
// O += P*V' (8 MFMA). No __syncthreads in the loop (per-wave LDS slices).
#define PLD 72   // padded P stride (elements); 144B rows keep 16B alignment

__global__ __launch_bounds__(256, 2) void attn(
    const unsigned short* __restrict__ Qb,
    const unsigned short* __restrict__ Kp,   // [h][m][k]
    const unsigned short* __restrict__ Vp,   // [h][k][m]
    float* __restrict__ vals) {
    const int bid = blockIdx.x;
    const int h  = bid >> 6;
    const int qt = bid & 63;
    const int lane = threadIdx.x & 63;
    const int wave = threadIdx.x >> 6;
    const int quad = lane >> 4, l16 = lane & 15;
    const size_t hoff = (size_t)h * HSLAB;

    const int qrow = qt * 64 + wave * 16 + l16;
    bf16x8 qf[2];
    qf[0] = *(const bf16x8*)&Qb[hoff + (size_t)qrow * DK + quad * 8];
    qf[1] = *(const bf16x8*)&Qb[hoff + (size_t)qrow * DK + 32 + quad * 8];

    f32x4 o[4] = {};
    float lsum[4] = {0.f, 0.f, 0.f, 0.f};

    __shared__ unsigned short Pb[4][16 * PLD];
    unsigned short* Pw = &Pb[wave][0];

    for (int m0 = 0; m0 < N_TOK; m0 += 64) {
        f32x4 s[4] = {};
        for (int ni = 0; ni < 4; ni++) {
            const unsigned short* kb = Kp + hoff + (size_t)(m0 + ni * 16 + l16) * DK + quad * 8;
            s[ni] = __builtin_amdgcn_mfma_f32_16x16x32_bf16(qf[0], *(const bf16x8*)kb,        s[ni], 0, 0, 0);
            s[ni] = __builtin_amdgcn_mfma_f32_16x16x32_bf16(qf[1], *(const bf16x8*)(kb + 32), s[ni], 0, 0, 0);
        }
        // exp (scale 1/64), accumulate per-lane partial row sums, stage P
        for (int ni = 0; ni < 4; ni++)
            for (int r = 0; r < 4; r++) {
                float p = __expf(s[ni][r] * 0.015625f);
                lsum[r] += p;
                Pw[(quad * 4 + r) * PLD + ni * 16 + l16] = f2bf(p);
            }
        // P in A-operand layout: A[m=l16][k=quad*8+j (+32)]
        bf16x8 pf0 = *(const bf16x8*)&Pw[l16 * PLD + quad * 8];
        bf16x8 pf1 = *(const bf16x8*)&Pw[l16 * PLD + 32 + quad * 8];
        for (int ni = 0; ni < 4; ni++) {
            const unsigned short* vb = Vp + hoff + (size_t)(ni * 16 + l16) * N_TOK + m0 + quad * 8;
            o[ni] = __builtin_amdgcn_mfma_f32_16x16x32_bf16(pf0, *(const bf16x8*)vb,        o[ni], 0, 0, 0);
            o[ni] = __builtin_amdgcn_mfma_f32_16x16x32_bf16(pf1, *(const bf16x8*)(vb + 32), o[ni], 0, 0, 0);
        }
    }

    // reduce row sums across the 16 lanes holding each C-row (xor 1,2,4,8)
    for (int r = 0; r < 4; r++) {
        float v = lsum[r];
        v += __shfl_xor(v, 1, 64);
        v += __shfl_xor(v, 2, 64);
        v += __shfl_xor(v, 4, 64);
        v += __shfl_xor(v, 8, 64);
        lsum[r] = 1.0f / v;
    }

    const int orow = qt * 64 + wave * 16 + quad * 4;
    for (int ni = 0; ni < 4; ni++)
        for (int r = 0; r < 4; r++)
            vals[hoff + (size_t)(orow + r) * DK + ni * 16 + l16] = o[ni][r] * lsum[r];
}

// --------------------------- residual + LayerNorm --------------------------
__global__ __launch_bounds__(256) void ln_kernel(
    const float* __restrict__ vals, const float* __restrict__ x,
    const float* __restrict__ gamma, const float* __restrict__ beta,
    float* __restrict__ out) {
    const int wave = threadIdx.x >> 6, lane = threadIdx.x & 63;
    const int row  = blockIdx.x * 4 + wave;
    const float* v  = vals + (size_t)row * D_MODEL;
    const float* xr = x    + (size_t)row * D_MODEL;

    float t[10];
    float s = 0.f;
    for (int i = 0; i < 10; i++) {
        t[i] = v[lane + i * 64] + xr[lane + i * 64];
        s += t[i];
    }
    for (int off = 32; off; off >>= 1) s += __shfl_xor(s, off, 64);
    float mean = s * (1.0f / 640.0f);
    float s2 = 0.f;
    for (int i = 0; i < 10; i++) { float d = t[i] - mean; s2 += d * d; }
    for (int off = 32; off; off >>= 1) s2 += __shfl_xor(s2, off, 64);
    float inv = rsqrtf(s2 * (1.0f / 640.0f) + 1e-5f);

    float* orow = out + (size_t)row * D_MODEL;
    for (int i = 0; i < 10; i++) {
        int c = lane + i * 64;
        orow[c] = (t[i] - mean) * inv * gamma[c] + beta[c];
    }
}

// ------------------------------- launcher ----------------------------------
extern "C" void kernel_launch(void* const* d_in, const int* in_sizes, int n_in,
                              void* d_out, int out_size, void* d_ws, size_t ws_size,
                              hipStream_t stream) {
    const float* x     = (const float*)d_in[0];
    const float* Wq    = (const float*)d_in[1];
    const float* Wk    = (const float*)d_in[2];
    const float* Wv    = (const float*)d_in[3];
    const float* gamma = (const float*)d_in[4];
    const float* beta  = (const float*)d_in[5];
    float* out = (float*)d_out;

    char* ws = (char*)d_ws;
    unsigned short* xb  = (unsigned short*)(ws);               // 5,242,880 B
    unsigned short* wqb = (unsigned short*)(ws + 5242880);     //   819,200 B
    unsigned short* wkb = (unsigned short*)(ws + 6062080);
    unsigned short* wvb = (unsigned short*)(ws + 6881280);
    unsigned short* Qb  = (unsigned short*)(ws + 7700480);     // 5,242,880 B
    unsigned short* Kp  = (unsigned short*)(ws + 12943360);    // K' [h][m][k]
    unsigned short* Vp  = (unsigned short*)(ws + 18186240);    // V' [h][k][m]
    float*          vals = (float*)(ws + 23429120);            // 10,485,760 B

    cvt_bf16<<<2560, 256, 0, stream>>>(x,  xb,  655360);
    cvt_bf16<<<400,  256, 0, stream>>>(Wq, wqb, 102400);
    cvt_bf16<<<400,  256, 0, stream>>>(Wk, wkb, 102400);
    cvt_bf16<<<400,  256, 0, stream>>>(Wv, wvb, 102400);

    gemm_qkv<<<dim3(5, 32, 3), 256, 0, stream>>>(xb, wqb, wkb, wvb, Qb, Kp, Vp);
    attn<<<640, 256, 0, stream>>>(Qb, Kp, Vp, vals);
    ln_kernel<<<1024, 256, 0, stream>>>(vals, x, gamma, beta, out);
}

// Round 2
// 450.108 us; speedup vs baseline: 1.0489x; 1.0489x over previous
//
#include <hip/hip_runtime.h>

// ---------------------------------------------------------------------------
// MHABlock: Q/K/V proj (bf16 MFMA, natural stores) -> per-head 64x4096
// transposes (K', V') -> split-K flash attention (no-max online softmax,
// logits ~N(0,0.125^2)), unnormalized atomic accumulation -> residual + LN
// with deferred softmax normalization.
// Flat-reshape quirks: Kflat viewed [10][64][4096] is Kh; K' = per-head
// transpose [4096][64]. Vflat viewed [10][4096][64] is Vh; V' = [64][4096].
// l_tot indexed by flat/64 group id: ln row q segment i uses l_tot[q*10+i].
// ---------------------------------------------------------------------------

typedef __bf16 bf16x8 __attribute__((ext_vector_type(8)));
typedef float  f32x4  __attribute__((ext_vector_type(4)));

#define N_TOK   4096
#define D_MODEL 640
#define DK      64
#define HSLAB   (N_TOK * DK)   // 262144 elements per head slab

__device__ __forceinline__ unsigned short f2bf(float f) {
    unsigned int u = __builtin_bit_cast(unsigned int, f);
    u += 0x7fffu + ((u >> 16) & 1u);          // round-to-nearest-even
    return (unsigned short)(u >> 16);
}

// -------------------------------- fp32 -> bf16 -----------------------------
__global__ __launch_bounds__(256) void cvt_bf16(const float* __restrict__ src,
                                                unsigned short* __restrict__ dst,
                                                int n4) {
    int i = blockIdx.x * 256 + threadIdx.x;
    if (i < n4) {
        float4 v = ((const float4*)src)[i];
        ushort4 o;
        o.x = f2bf(v.x); o.y = f2bf(v.y); o.z = f2bf(v.z); o.w = f2bf(v.w);
        ((ushort4*)dst)[i] = o;
    }
}

// ------------------------ QKV NT-GEMM: C = x @ W^T -------------------------
// M=4096, N=640, K=640. 128x128 tile, BK=32, 4 waves each 64x64.
// All modes store naturally (row-major [N_TOK][D_MODEL]).
#define BM  128
#define BN  128
#define BKK 32
#define LDT 40

__global__ __launch_bounds__(256, 2) void gemm_qkv(
    const unsigned short* __restrict__ xb,
    const unsigned short* __restrict__ wq,
    const unsigned short* __restrict__ wk,
    const unsigned short* __restrict__ wv,
    unsigned short* __restrict__ Qo,
    unsigned short* __restrict__ Ko,
    unsigned short* __restrict__ Vo) {
    const int mode = blockIdx.z;
    const unsigned short* W = (mode == 0) ? wq : (mode == 1) ? wk : wv;
    unsigned short*       C = (mode == 0) ? Qo : (mode == 1) ? Ko : Vo;
    const int m0 = blockIdx.y * BM;
    const int n0 = blockIdx.x * BN;

    __shared__ unsigned short As[BM * LDT];
    __shared__ unsigned short Bs[BN * LDT];

    const int tid  = threadIdx.x;
    const int lane = tid & 63;
    const int wave = tid >> 6;
    const int quad = lane >> 4, l16 = lane & 15;
    const int wm = (wave >> 1) * 64, wn = (wave & 1) * 64;

    f32x4 acc[4][4] = {};

    const int c0 = tid, c1 = tid + 256;
    const int r0 = c0 >> 2, k0o = (c0 & 3) << 3;
    const int r1 = c1 >> 2, k1o = (c1 & 3) << 3;

    for (int kt = 0; kt < D_MODEL; kt += BKK) {
        __syncthreads();
        *(bf16x8*)&As[r0 * LDT + k0o] = *(const bf16x8*)&xb[(size_t)(m0 + r0) * D_MODEL + kt + k0o];
        *(bf16x8*)&As[r1 * LDT + k1o] = *(const bf16x8*)&xb[(size_t)(m0 + r1) * D_MODEL + kt + k1o];
        *(bf16x8*)&Bs[r0 * LDT + k0o] = *(const bf16x8*)&W [(size_t)(n0 + r0) * D_MODEL + kt + k0o];
        *(bf16x8*)&Bs[r1 * LDT + k1o] = *(const bf16x8*)&W [(size_t)(n0 + r1) * D_MODEL + kt + k1o];
        __syncthreads();

        bf16x8 af[4], bfr[4];
        for (int mi = 0; mi < 4; mi++)
            af[mi] = *(const bf16x8*)&As[(wm + mi * 16 + l16) * LDT + quad * 8];
        for (int ni = 0; ni < 4; ni++)
            bfr[ni] = *(const bf16x8*)&Bs[(wn + ni * 16 + l16) * LDT + quad * 8];
        for (int mi = 0; mi < 4; mi++)
            for (int ni = 0; ni < 4; ni++)
                acc[mi][ni] = __builtin_amdgcn_mfma_f32_16x16x32_bf16(af[mi], bfr[ni], acc[mi][ni], 0, 0, 0);
    }

    for (int mi = 0; mi < 4; mi++)
        for (int ni = 0; ni < 4; ni++)
            for (int r = 0; r < 4; r++) {
                int row = m0 + wm + mi * 16 + quad * 4 + r;
                int col = n0 + wn + ni * 16 + l16;
                C[(size_t)row * D_MODEL + col] = f2bf(acc[mi][ni][r]);
            }
}

// ------------------- per-head transpose: src[R][C] -> dst[C][R] ------------
// grid (C/64, R/64, heads), 256 threads, 64x64 tiles.
__global__ __launch_bounds__(256) void transpose_hd(
    const unsigned short* __restrict__ src, unsigned short* __restrict__ dst,
    int R, int C) {
    __shared__ unsigned short T[64][66];   // 132B rows: ~2-way wr, 4-way rd
    const size_t hb = (size_t)blockIdx.z * HSLAB;
    const int r0 = blockIdx.y * 64, c0 = blockIdx.x * 64;
    const int t = threadIdx.x;
    const int rr = t >> 3, c8 = (t & 7) * 8;

    for (int hf = 0; hf < 2; hf++) {
        int r = rr + hf * 32;
        bf16x8 v = *(const bf16x8*)&src[hb + (size_t)(r0 + r) * C + c0 + c8];
        for (int j = 0; j < 8; j++) T[r][c8 + j] = ((unsigned short*)&v)[j];
    }
    __syncthreads();
    for (int hf = 0; hf < 2; hf++) {
        int oc = rr + hf * 32;            // out row = original col
        unsigned short v[8];
        for (int j = 0; j < 8; j++) v[j] = T[c8 + j][oc];
        *(bf16x8*)&dst[hb + (size_t)(c0 + oc) * R + r0 + c8] = *(bf16x8*)v;
    }
}

// ------------------------------- attention ---------------------------------
// grid (640, 4): x = head*64 + qtile, y = kpart (1024 keys each).
// 4 waves x 16 Q rows. Unnormalized O and row-sums accumulated via fp32
// atomics (linear combine is exact: no max-rescaling in this softmax).
#define PLD 72

__global__ __launch_bounds__(256, 8) void attn(
    const unsigned short* __restrict__ Qb,
    const unsigned short* __restrict__ Kp,   // [h][m][k]
    const unsigned short* __restrict__ Vp,   // [h][k][m]
    float* __restrict__ vals,                // [h][q][dk] fp32, pre-zeroed
    float* __restrict__ l_tot) {             // [h*4096+q] fp32, pre-zeroed
    const int bid = blockIdx.x;
    const int h  = bid >> 6;
    const int qt = bid & 63;
    const int kbase = blockIdx.y << 10;
    const int lane = threadIdx.x & 63;
    const int wave = threadIdx.x >> 6;
    const int quad = lane >> 4, l16 = lane & 15;
    const size_t hoff = (size_t)h * HSLAB;

    const int qrow = qt * 64 + wave * 16 + l16;
    bf16x8 qf[2];
    qf[0] = *(const bf16x8*)&Qb[hoff + (size_t)qrow * DK + quad * 8];
    qf[1] = *(const bf16x8*)&Qb[hoff + (size_t)qrow * DK + 32 + quad * 8];

    f32x4 o[4] = {};
    float lsum[4] = {0.f, 0.f, 0.f, 0.f};

    __shared__ unsigned short Pb[4][16 * PLD];
    unsigned short* Pw = &Pb[wave][0];

    for (int it = 0; it < 16; it++) {
        const int m0 = kbase + it * 64;
        f32x4 s[4] = {};
        for (int ni = 0; ni < 4; ni++) {
            const unsigned short* kb = Kp + hoff + (size_t)(m0 + ni * 16 + l16) * DK + quad * 8;
            s[ni] = __builtin_amdgcn_mfma_f32_16x16x32_bf16(qf[0], *(const bf16x8*)kb,        s[ni], 0, 0, 0);
            s[ni] = __builtin_amdgcn_mfma_f32_16x16x32_bf16(qf[1], *(const bf16x8*)(kb + 32), s[ni], 0, 0, 0);
        }
        for (int ni = 0; ni < 4; ni++)
            for (int r = 0; r < 4; r++) {
                float p = __expf(s[ni][r] * 0.015625f);
                lsum[r] += p;
                Pw[(quad * 4 + r) * PLD + ni * 16 + l16] = f2bf(p);
            }
        bf16x8 pf0 = *(const bf16x8*)&Pw[l16 * PLD + quad * 8];
        bf16x8 pf1 = *(const bf16x8*)&Pw[l16 * PLD + 32 + quad * 8];
        for (int ni = 0; ni < 4; ni++) {
            const unsigned short* vb = Vp + hoff + (size_t)(ni * 16 + l16) * N_TOK + m0 + quad * 8;
            o[ni] = __builtin_amdgcn_mfma_f32_16x16x32_bf16(pf0, *(const bf16x8*)vb,        o[ni], 0, 0, 0);
            o[ni] = __builtin_amdgcn_mfma_f32_16x16x32_bf16(pf1, *(const bf16x8*)(vb + 32), o[ni], 0, 0, 0);
        }
    }

    for (int r = 0; r < 4; r++) {
        float v = lsum[r];
        v += __shfl_xor(v, 1, 64);
        v += __shfl_xor(v, 2, 64);
        v += __shfl_xor(v, 4, 64);
        v += __shfl_xor(v, 8, 64);
        lsum[r] = v;
    }

    const int orow = qt * 64 + wave * 16 + quad * 4;
    for (int ni = 0; ni < 4; ni++)
        for (int r = 0; r < 4; r++)
            atomicAdd(&vals[hoff + (size_t)(orow + r) * DK + ni * 16 + l16], o[ni][r]);
    if (l16 == 0)
        for (int r = 0; r < 4; r++)
            atomicAdd(&l_tot[(h << 12) + orow + r], lsum[r]);
}

// ----------------- deferred normalize + residual + LayerNorm ---------------
__global__ __launch_bounds__(256) void ln_kernel(
    const float* __restrict__ vals, const float* __restrict__ l_tot,
    const float* __restrict__ x,
    const float* __restrict__ gamma, const float* __restrict__ beta,
    float* __restrict__ out) {
    const int wave = threadIdx.x >> 6, lane = threadIdx.x & 63;
    const int row  = blockIdx.x * 4 + wave;
    const float* v  = vals + (size_t)row * D_MODEL;   // flat identical layout
    const float* xr = x    + (size_t)row * D_MODEL;

    float t[10];
    float s = 0.f;
    for (int i = 0; i < 10; i++) {
        float linv = 1.0f / l_tot[row * 10 + i];      // wave-uniform
        t[i] = v[lane + i * 64] * linv + xr[lane + i * 64];
        s += t[i];
    }
    for (int off = 32; off; off >>= 1) s += __shfl_xor(s, off, 64);
    float mean = s * (1.0f / 640.0f);
    float s2 = 0.f;
    for (int i = 0; i < 10; i++) { float d = t[i] - mean; s2 += d * d; }
    for (int off = 32; off; off >>= 1) s2 += __shfl_xor(s2, off, 64);
    float inv = rsqrtf(s2 * (1.0f / 640.0f) + 1e-5f);

    float* orow = out + (size_t)row * D_MODEL;
    for (int i = 0; i < 10; i++) {
        int c = lane + i * 64;
        orow[c] = (t[i] - mean) * inv * gamma[c] + beta[c];
    }
}

// ------------------------------- launcher ----------------------------------
extern "C" void kernel_launch(void* const* d_in, const int* in_sizes, int n_in,
                              void* d_out, int out_size, void* d_ws, size_t ws_size,
                              hipStream_t stream) {
    const float* x     = (const float*)d_in[0];
    const float* Wq    = (const float*)d_in[1];
    const float* Wk    = (const float*)d_in[2];
    const float* Wv    = (const float*)d_in[3];
    const float* gamma = (const float*)d_in[4];
    const float* beta  = (const float*)d_in[5];
    float* out = (float*)d_out;

    char* ws = (char*)d_ws;
    unsigned short* xb  = (unsigned short*)(ws);               // 5,242,880 B
    unsigned short* wqb = (unsigned short*)(ws + 5242880);     //   819,200 B each
    unsigned short* wkb = (unsigned short*)(ws + 6062080);
    unsigned short* wvb = (unsigned short*)(ws + 6881280);
    unsigned short* Qb  = (unsigned short*)(ws + 7700480);     // 5,242,880 B
    unsigned short* Kp  = (unsigned short*)(ws + 12943360);    // K' [h][m][k]
    unsigned short* Vp  = (unsigned short*)(ws + 18186240);    // V' [h][k][m]
    // Kn/Vn (natural K,V) alias the vals region: dead before memset runs.
    unsigned short* Kn  = (unsigned short*)(ws + 23429120);    // 5,242,880 B
    unsigned short* Vn  = (unsigned short*)(ws + 28672000);    // 5,242,880 B
    float*          vals = (float*)(ws + 23429120);            // 10,485,760 B
    // l_tot reuses the dead wqb bf16 region (gemm done by then).
    float*          l_tot = (float*)(ws + 5242880);            //   163,840 B

    cvt_bf16<<<2560, 256, 0, stream>>>(x,  xb,  655360);
    cvt_bf16<<<400,  256, 0, stream>>>(Wq, wqb, 102400);
    cvt_bf16<<<400,  256, 0, stream>>>(Wk, wkb, 102400);
    cvt_bf16<<<400,  256, 0, stream>>>(Wv, wvb, 102400);

    gemm_qkv<<<dim3(5, 32, 3), 256, 0, stream>>>(xb, wqb, wkb, wvb, Qb, Kn, Vn);

    transpose_hd<<<dim3(64, 1, 10), 256, 0, stream>>>(Kn, Kp, 64, 4096);
    transpose_hd<<<dim3(1, 64, 10), 256, 0, stream>>>(Vn, Vp, 4096, 64);

    hipMemsetAsync(vals,  0, 10485760, stream);   // also retires Kn/Vn
    hipMemsetAsync(l_tot, 0, 163840,   stream);

    attn<<<dim3(640, 4), 256, 0, stream>>>(Qb, Kp, Vp, vals, l_tot);
    ln_kernel<<<1024, 256, 0, stream>>>(vals, l_tot, x, gamma, beta, out);
}

// Round 3
// 195.453 us; speedup vs baseline: 2.4156x; 2.3029x over previous
//
#include <hip/hip_runtime.h>

// ---------------------------------------------------------------------------
// MHABlock: Q/K/V proj (bf16 MFMA) -> per-head transposes (K',V') ->
// LDS-staged split-K flash attention (no-max online softmax, logits
// ~N(0,0.125^2)) with S^T = K*Q^T trick for cheap P layout transform ->
// deferred normalize + residual + LayerNorm.
// K'[h][m][k], V'[h][k][m]; K/V tiles staged to LDS via global_load_lds
// (width 16) with XOR chunk swizzle -> conflict-free ds_read_b128 fragments.
// ---------------------------------------------------------------------------

typedef __bf16 bf16x8 __attribute__((ext_vector_type(8)));
typedef float  f32x4  __attribute__((ext_vector_type(4)));
typedef unsigned short u16x4 __attribute__((ext_vector_type(4)));

#define N_TOK   4096
#define D_MODEL 640
#define DK      64
#define HSLAB   (N_TOK * DK)

__device__ __forceinline__ unsigned short f2bf(float f) {
    unsigned int u = __builtin_bit_cast(unsigned int, f);
    u += 0x7fffu + ((u >> 16) & 1u);
    return (unsigned short)(u >> 16);
}

__device__ __forceinline__ void stage16(const unsigned short* g, unsigned short* lds_uniform) {
    __builtin_amdgcn_global_load_lds(
        (const __attribute__((address_space(1))) unsigned int*)g,
        (__attribute__((address_space(3))) unsigned int*)lds_uniform, 16, 0, 0);
}

// -------------------------------- fp32 -> bf16 -----------------------------
__global__ __launch_bounds__(256) void cvt_bf16(const float* __restrict__ src,
                                                unsigned short* __restrict__ dst,
                                                int n4) {
    int i = blockIdx.x * 256 + threadIdx.x;
    if (i < n4) {
        float4 v = ((const float4*)src)[i];
        ushort4 o;
        o.x = f2bf(v.x); o.y = f2bf(v.y); o.z = f2bf(v.z); o.w = f2bf(v.w);
        ((ushort4*)dst)[i] = o;
    }
}

__global__ __launch_bounds__(256) void cvt_bf16_w(const float* __restrict__ w0,
                                                  const float* __restrict__ w1,
                                                  const float* __restrict__ w2,
                                                  unsigned short* __restrict__ d0,
                                                  unsigned short* __restrict__ d1,
                                                  unsigned short* __restrict__ d2) {
    const float* s = (blockIdx.y == 0) ? w0 : (blockIdx.y == 1) ? w1 : w2;
    unsigned short* d = (blockIdx.y == 0) ? d0 : (blockIdx.y == 1) ? d1 : d2;
    int i = blockIdx.x * 256 + threadIdx.x;
    float4 v = ((const float4*)s)[i];
    ushort4 o;
    o.x = f2bf(v.x); o.y = f2bf(v.y); o.z = f2bf(v.z); o.w = f2bf(v.w);
    ((ushort4*)d)[i] = o;
}

// ------------------------ QKV NT-GEMM: C = x @ W^T -------------------------
#define BM  128
#define BN  128
#define BKK 32
#define LDT 40

__global__ __launch_bounds__(256, 2) void gemm_qkv(
    const unsigned short* __restrict__ xb,
    const unsigned short* __restrict__ wq,
    const unsigned short* __restrict__ wk,
    const unsigned short* __restrict__ wv,
    unsigned short* __restrict__ Qo,
    unsigned short* __restrict__ Ko,
    unsigned short* __restrict__ Vo) {
    const int mode = blockIdx.z;
    const unsigned short* W = (mode == 0) ? wq : (mode == 1) ? wk : wv;
    unsigned short*       C = (mode == 0) ? Qo : (mode == 1) ? Ko : Vo;
    const int m0 = blockIdx.y * BM;
    const int n0 = blockIdx.x * BN;

    __shared__ unsigned short As[BM * LDT];
    __shared__ unsigned short Bs[BN * LDT];

    const int tid  = threadIdx.x;
    const int lane = tid & 63;
    const int wave = tid >> 6;
    const int quad = lane >> 4, l16 = lane & 15;
    const int wm = (wave >> 1) * 64, wn = (wave & 1) * 64;

    f32x4 acc[4][4] = {};

    const int c0 = tid, c1 = tid + 256;
    const int r0 = c0 >> 2, k0o = (c0 & 3) << 3;
    const int r1 = c1 >> 2, k1o = (c1 & 3) << 3;

    for (int kt = 0; kt < D_MODEL; kt += BKK) {
        __syncthreads();
        *(bf16x8*)&As[r0 * LDT + k0o] = *(const bf16x8*)&xb[(size_t)(m0 + r0) * D_MODEL + kt + k0o];
        *(bf16x8*)&As[r1 * LDT + k1o] = *(const bf16x8*)&xb[(size_t)(m0 + r1) * D_MODEL + kt + k1o];
        *(bf16x8*)&Bs[r0 * LDT + k0o] = *(const bf16x8*)&W [(size_t)(n0 + r0) * D_MODEL + kt + k0o];
        *(bf16x8*)&Bs[r1 * LDT + k1o] = *(const bf16x8*)&W [(size_t)(n0 + r1) * D_MODEL + kt + k1o];
        __syncthreads();

        bf16x8 af[4], bfr[4];
        for (int mi = 0; mi < 4; mi++)
            af[mi] = *(const bf16x8*)&As[(wm + mi * 16 + l16) * LDT + quad * 8];
        for (int ni = 0; ni < 4; ni++)
            bfr[ni] = *(const bf16x8*)&Bs[(wn + ni * 16 + l16) * LDT + quad * 8];
        for (int mi = 0; mi < 4; mi++)
            for (int ni = 0; ni < 4; ni++)
                acc[mi][ni] = __builtin_amdgcn_mfma_f32_16x16x32_bf16(af[mi], bfr[ni], acc[mi][ni], 0, 0, 0);
    }

    for (int mi = 0; mi < 4; mi++)
        for (int ni = 0; ni < 4; ni++)
            for (int r = 0; r < 4; r++) {
                int row = m0 + wm + mi * 16 + quad * 4 + r;
                int col = n0 + wn + ni * 16 + l16;
                C[(size_t)row * D_MODEL + col] = f2bf(acc[mi][ni][r]);
            }
}

// ------------------- per-head transpose: src[R][C] -> dst[C][R] ------------
__global__ __launch_bounds__(256) void transpose_hd(
    const unsigned short* __restrict__ src, unsigned short* __restrict__ dst,
    int R, int C) {
    __shared__ unsigned short T[64][66];
    const size_t hb = (size_t)blockIdx.z * HSLAB;
    const int r0 = blockIdx.y * 64, c0 = blockIdx.x * 64;
    const int t = threadIdx.x;
    const int rr = t >> 3, c8 = (t & 7) * 8;

    for (int hf = 0; hf < 2; hf++) {
        int r = rr + hf * 32;
        bf16x8 v = *(const bf16x8*)&src[hb + (size_t)(r0 + r) * C + c0 + c8];
        for (int j = 0; j < 8; j++) T[r][c8 + j] = ((unsigned short*)&v)[j];
    }
    __syncthreads();
    for (int hf = 0; hf < 2; hf++) {
        int oc = rr + hf * 32;
        unsigned short v[8];
        for (int j = 0; j < 8; j++) v[j] = T[c8 + j][oc];
        *(bf16x8*)&dst[hb + (size_t)(c0 + oc) * R + r0 + c8] = *(bf16x8*)v;
    }
}

// ------------------------------- attention ---------------------------------
// grid (320, 4): x = head*32 + qtile(128 rows), y = kpart (1024 keys).
// 4 waves x 32 q-rows (2 fragment groups). Per 64-key iteration:
//   stage K-tile (64x64) + V-tile (64x64) into LDS (global_load_lds w=16,
//   XOR chunk swizzle), S^T = K*Q^T (16 MFMA), exp, P[q][key] via b64
//   writes, O += P*V (16 MFMA). Unnormalized O/l accumulated via atomics.
#define PLD 72

__global__ __launch_bounds__(256, 4) void attn(
    const unsigned short* __restrict__ Qb,
    const unsigned short* __restrict__ Kp,   // [h][m][k]
    const unsigned short* __restrict__ Vp,   // [h][k][m]
    float* __restrict__ vals,                // [h][q][dk] fp32, pre-zeroed
    float* __restrict__ l_tot) {             // [h*4096+q] fp32, pre-zeroed
    const int h  = blockIdx.x >> 5;
    const int qt = blockIdx.x & 31;
    const int kbase = blockIdx.y << 10;
    const int lane = threadIdx.x & 63;
    const int wave = threadIdx.x >> 6;
    const int quad = lane >> 4, l16 = lane & 15;
    const size_t hoff = (size_t)h * HSLAB;

    __shared__ unsigned short Kt[4096];          // 64 rows x 64, swizzled
    __shared__ unsigned short Vt[4096];
    __shared__ unsigned short Pb[4][32 * PLD];
    unsigned short* Pw = &Pb[wave][0];

    // Q fragments (B-operand: l16 = q row), 32 q-rows per wave
    const int qbase = qt * 128 + wave * 32;
    bf16x8 qf[2][2];
    for (int g = 0; g < 2; g++)
        for (int kh = 0; kh < 2; kh++)
            qf[g][kh] = *(const bf16x8*)&Qb[hoff + (size_t)(qbase + g * 16 + l16) * DK + kh * 32 + quad * 8];

    f32x4 o[2][4] = {};
    float lsum[2] = {0.f, 0.f};

    // staging geometry: 8 instrs of 64 chunks; this wave's two slots
    const int s0 = wave * 128 + lane;            // j=0 chunk id
    const int s1 = s0 + 64;                      // j=1 chunk id
    const int kr0 = s0 >> 3, kc0 = (s0 & 7) ^ (kr0 & 7);
    const int kr1 = s1 >> 3, kc1 = (s1 & 7) ^ (kr1 & 7);
    const int swz = l16 & 7;                     // fragment-read swizzle

    for (int it = 0; it < 16; it++) {
        const int m0 = kbase + it * 64;
        __syncthreads();
        stage16(Kp + hoff + (size_t)(m0 + kr0) * DK + kc0 * 8, Kt + wave * 1024);
        stage16(Kp + hoff + (size_t)(m0 + kr1) * DK + kc1 * 8, Kt + wave * 1024 + 512);
        stage16(Vp + hoff + (size_t)kr0 * N_TOK + m0 + kc0 * 8, Vt + wave * 1024);
        stage16(Vp + hoff + (size_t)kr1 * N_TOK + m0 + kc1 * 8, Vt + wave * 1024 + 512);
        __syncthreads();

        // ---- S^T tiles: A = K rows (key), B = Q rows (q) ----
        for (int ni = 0; ni < 4; ni++) {
            const int krow = ni * 16 + l16;
            bf16x8 a0 = *(const bf16x8*)&Kt[krow * 64 + ((0 + quad) ^ swz) * 8];
            bf16x8 a1 = *(const bf16x8*)&Kt[krow * 64 + ((4 + quad) ^ swz) * 8];
            for (int g = 0; g < 2; g++) {
                f32x4 s = {};
                s = __builtin_amdgcn_mfma_f32_16x16x32_bf16(a0, qf[g][0], s, 0, 0, 0);
                s = __builtin_amdgcn_mfma_f32_16x16x32_bf16(a1, qf[g][1], s, 0, 0, 0);
                // lane holds S^T[key=ni*16+quad*4+r][q=g*16+l16]
                u16x4 pk;
                for (int r = 0; r < 4; r++) {
                    float p = __expf(s[r] * 0.015625f);
                    lsum[g] += p;
                    pk[r] = f2bf(p);
                }
                *(u16x4*)&Pw[(g * 16 + l16) * PLD + ni * 16 + quad * 4] = pk;
            }
        }

        // ---- P A-fragments (conflict-free b128) ----
        bf16x8 pf[2][2];
        for (int g = 0; g < 2; g++)
            for (int mh = 0; mh < 2; mh++)
                pf[g][mh] = *(const bf16x8*)&Pw[(g * 16 + l16) * PLD + mh * 32 + quad * 8];

        // ---- O += P * V : B = V rows (dk) ----
        for (int nd = 0; nd < 4; nd++) {
            const int vrow = nd * 16 + l16;
            bf16x8 b0 = *(const bf16x8*)&Vt[vrow * 64 + ((0 + quad) ^ swz) * 8];
            bf16x8 b1 = *(const bf16x8*)&Vt[vrow * 64 + ((4 + quad) ^ swz) * 8];
            for (int g = 0; g < 2; g++) {
                o[g][nd] = __builtin_amdgcn_mfma_f32_16x16x32_bf16(pf[g][0], b0, o[g][nd], 0, 0, 0);
                o[g][nd] = __builtin_amdgcn_mfma_f32_16x16x32_bf16(pf[g][1], b1, o[g][nd], 0, 0, 0);
            }
        }
    }

    // row sums: reduce over quads (lane bits 4,5)
    for (int g = 0; g < 2; g++) {
        float v = lsum[g];
        v += __shfl_xor(v, 16, 64);
        v += __shfl_xor(v, 32, 64);
        if (lane < 16)
            atomicAdd(&l_tot[(h << 12) + qbase + g * 16 + l16], v);
    }

    // O: C-layout row = q offset quad*4+r, col = dk = nd*16+l16
    for (int g = 0; g < 2; g++)
        for (int nd = 0; nd < 4; nd++)
            for (int r = 0; r < 4; r++) {
                int q = qbase + g * 16 + quad * 4 + r;
                atomicAdd(&vals[hoff + (size_t)q * DK + nd * 16 + l16], o[g][nd][r]);
            }
}

// ----------------- deferred normalize + residual + LayerNorm ---------------
__global__ __launch_bounds__(256) void ln_kernel(
    const float* __restrict__ vals, const float* __restrict__ l_tot,
    const float* __restrict__ x,
    const float* __restrict__ gamma, const float* __restrict__ beta,
    float* __restrict__ out) {
    const int wave = threadIdx.x >> 6, lane = threadIdx.x & 63;
    const int row  = blockIdx.x * 4 + wave;
    const float* v  = vals + (size_t)row * D_MODEL;
    const float* xr = x    + (size_t)row * D_MODEL;

    float t[10];
    float s = 0.f;
    for (int i = 0; i < 10; i++) {
        float linv = 1.0f / l_tot[row * 10 + i];
        t[i] = v[lane + i * 64] * linv + xr[lane + i * 64];
        s += t[i];
    }
    for (int off = 32; off; off >>= 1) s += __shfl_xor(s, off, 64);
    float mean = s * (1.0f / 640.0f);
    float s2 = 0.f;
    for (int i = 0; i < 10; i++) { float d = t[i] - mean; s2 += d * d; }
    for (int off = 32; off; off >>= 1) s2 += __shfl_xor(s2, off, 64);
    float inv = rsqrtf(s2 * (1.0f / 640.0f) + 1e-5f);

    float* orow = out + (size_t)row * D_MODEL;
    for (int i = 0; i < 10; i++) {
        int c = lane + i * 64;
        orow[c] = (t[i] - mean) * inv * gamma[c] + beta[c];
    }
}

// ------------------------------- launcher ----------------------------------
extern "C" void kernel_launch(void* const* d_in, const int* in_sizes, int n_in,
                              void* d_out, int out_size, void* d_ws, size_t ws_size,
                              hipStream_t stream) {
    const float* x     = (const float*)d_in[0];
    const float* Wq    = (const float*)d_in[1];
    const float* Wk    = (const float*)d_in[2];
    const float* Wv    = (const float*)d_in[3];
    const float* gamma = (const float*)d_in[4];
    const float* beta  = (const float*)d_in[5];
    float* out = (float*)d_out;

    char* ws = (char*)d_ws;
    unsigned short* xb  = (unsigned short*)(ws);               // 5,242,880 B
    unsigned short* wqb = (unsigned short*)(ws + 5242880);
    unsigned short* wkb = (unsigned short*)(ws + 6062080);
    unsigned short* wvb = (unsigned short*)(ws + 6881280);
    unsigned short* Qb  = (unsigned short*)(ws + 7700480);
    unsigned short* Kp  = (unsigned short*)(ws + 12943360);    // K' [h][m][k]
    unsigned short* Vp  = (unsigned short*)(ws + 18186240);    // V' [h][k][m]
    unsigned short* Kn  = (unsigned short*)(ws + 23429120);    // aliases vals
    unsigned short* Vn  = (unsigned short*)(ws + 28672000);
    float*          vals = (float*)(ws + 23429120);
    float*          l_tot = (float*)(ws + 5242880);            // dead wqb

    cvt_bf16<<<2560, 256, 0, stream>>>(x, xb, 655360);
    cvt_bf16_w<<<dim3(400, 3), 256, 0, stream>>>(Wq, Wk, Wv, wqb, wkb, wvb);

    gemm_qkv<<<dim3(5, 32, 3), 256, 0, stream>>>(xb, wqb, wkb, wvb, Qb, Kn, Vn);

    transpose_hd<<<dim3(64, 1, 10), 256, 0, stream>>>(Kn, Kp, 64, 4096);
    transpose_hd<<<dim3(1, 64, 10), 256, 0, stream>>>(Vn, Vp, 4096, 64);

    hipMemsetAsync(vals,  0, 10485760, stream);
    hipMemsetAsync(l_tot, 0, 163840,   stream);

    attn<<<dim3(320, 4), 256, 0, stream>>>(Qb, Kp, Vp, vals, l_tot);
    ln_kernel<<<1024, 256, 0, stream>>>(vals, l_tot, x, gamma, beta, out);
}